// Round 1
// baseline (538.213 us; speedup 1.0000x reference)
//
#include <hip/hip_runtime.h>
#include <hip/hip_fp16.h>

#define D 4096
#define KSEL 32

struct Pair { unsigned idx; float w; };

// Table layout in d_ws (units: Pair, 8 B). Transposed [k][neuron] per matrix.
constexpr int OFF_E0 = 0;        // 32 x 2048
constexpr int OFF_I0 = 65536;    // 32 x 2048
constexpr int OFF_E1 = 131072;   // 32 x 512
constexpr int OFF_I1 = 147456;   // 32 x 512
constexpr int OFF_ES = 163840;   // 32 x 128
constexpr int OFF_IS = 167936;   // 32 x 128
// total 172032 Pairs = 1,376,256 bytes of workspace

// ---------------------------------------------------------------------------
// Kernel 1: stable top-32 per row -> (idx, exp(val)) tables.
// One block per row. Each thread caches its 16 elements in registers and its
// local argmax; per iteration only the winning thread rescans.
// Tie-break: larger value wins; on equal value, SMALLER index wins (matches
// jax.lax.top_k stability -> identical selected set at the rank-32 boundary).
// ---------------------------------------------------------------------------
__global__ __launch_bounds__(256) void topk_kernel(
    const float* __restrict__ e0, const float* __restrict__ i0,
    const float* __restrict__ e1, const float* __restrict__ i1,
    const float* __restrict__ es, const float* __restrict__ is_,
    Pair* __restrict__ table)
{
  const int r = blockIdx.x;
  const float* src; int j; Pair* out; int N;
  if (r < 2048)      { src = e0 + (size_t)r*D;        j = r;      out = table + OFF_E0; N = 2048; }
  else if (r < 4096) { src = i0 + (size_t)(r-2048)*D; j = r-2048; out = table + OFF_I0; N = 2048; }
  else if (r < 4608) { src = e1 + (size_t)(r-4096)*D; j = r-4096; out = table + OFF_E1; N = 512; }
  else if (r < 5120) { src = i1 + (size_t)(r-4608)*D; j = r-4608; out = table + OFF_I1; N = 512; }
  else if (r < 5248) { src = es + (size_t)(r-5120)*D; j = r-5120; out = table + OFF_ES; N = 128; }
  else               { src = is_ + (size_t)(r-5248)*D; j = r-5248; out = table + OFF_IS; N = 128; }

  const int t = threadIdx.x;
  const int wave = t >> 6, lane = t & 63;

  float v[16];
  #pragma unroll
  for (int u = 0; u < 16; ++u) v[u] = src[t + 256*u];   // coalesced, idx = t + 256*u

  __shared__ float s_val[4];
  __shared__ unsigned s_idx[4];
  __shared__ float sb_val;
  __shared__ unsigned sb_idx;

  // initial cached local best (ascending u + strict '>' keeps smallest idx on tie)
  float bv = -1e30f; unsigned bi = 0xFFFFFFFFu;
  #pragma unroll
  for (int u = 0; u < 16; ++u) {
    if (v[u] > bv) { bv = v[u]; bi = (unsigned)(t + (u << 8)); }
  }

  for (int k = 0; k < KSEL; ++k) {
    // wave butterfly argmax (val desc, idx asc)
    float rv = bv; unsigned ri = bi;
    #pragma unroll
    for (int off = 32; off >= 1; off >>= 1) {
      float ov   = __shfl_xor(rv, off);
      unsigned oi = __shfl_xor(ri, off);
      if (ov > rv || (ov == rv && oi < ri)) { rv = ov; ri = oi; }
    }
    if (lane == 0) { s_val[wave] = rv; s_idx[wave] = ri; }
    __syncthreads();
    if (t == 0) {
      float Bv = s_val[0]; unsigned Bi = s_idx[0];
      #pragma unroll
      for (int w = 1; w < 4; ++w) {
        float ov = s_val[w]; unsigned oi = s_idx[w];
        if (ov > Bv || (ov == Bv && oi < Bi)) { Bv = ov; Bi = oi; }
      }
      sb_val = Bv; sb_idx = Bi;
      out[k*N + j] = Pair{Bi, expf(Bv)};
    }
    __syncthreads();
    const unsigned gbi = sb_idx;
    if ((gbi & 255u) == (unsigned)t) {
      // I owned the winner: consume it and rescan my 16 (static indices only)
      bv = -1e30f; bi = 0xFFFFFFFFu;
      #pragma unroll
      for (int u = 0; u < 16; ++u) {
        const unsigned myidx = (unsigned)(t + (u << 8));
        if (myidx == gbi) { v[u] = -1e30f; }
        else if (v[u] > bv) { bv = v[u]; bi = myidx; }
      }
    }
    // no extra barrier needed: next iter's s_val write is fenced by the
    // __syncthreads() above before t0 overwrites sb_idx again
  }
}

// ---------------------------------------------------------------------------
// Kernel 2: fully fused forward for 4 batch rows per block.
// LDS: x/inh staged column-major as float4 (4 batches per column) so one
// ds_read_b128 gathers all 4 batches' values for a synapse. h0/h1 in f16.
// ---------------------------------------------------------------------------
__global__ __launch_bounds__(512) void fused_kernel(
    const float* __restrict__ x, const float* __restrict__ inh,
    const float* __restrict__ bw1, const float* __restrict__ bws,
    const float* __restrict__ vthp, const float* __restrict__ lam,
    const Pair* __restrict__ table, float* __restrict__ out)
{
  __shared__ float4 sx[D];          // 64 KiB: sx[c] = {x[b0..b3, c]}
  __shared__ float4 si[D];          // 64 KiB
  __shared__ __half h0[2048][4];    // 16 KiB
  __shared__ __half h1[512][4];     //  4 KiB   -> 148 KiB total

  const int t = threadIdx.x;
  const size_t b0 = (size_t)blockIdx.x * 4;

  // stage 4 rows of x and inh, transposed to per-column float4
  #pragma unroll
  for (int jj = 0; jj < 4; ++jj) {
    const float* rx = x   + (b0 + jj)*D;
    const float* ri = inh + (b0 + jj)*D;
    #pragma unroll
    for (int i = 0; i < 8; ++i) {
      const int c = t + 512*i;
      ((float*)&sx[c])[jj] = rx[c];
      ((float*)&si[c])[jj] = ri[c];
    }
  }
  __syncthreads();

  auto dot32 = [](const Pair* __restrict__ tb, int stride, const float4* __restrict__ lds) {
    float4 acc = {0.f, 0.f, 0.f, 0.f};
    #pragma unroll 8
    for (int k = 0; k < KSEL; ++k) {
      const Pair p = tb[k*stride];
      const float4 xv = lds[p.idx];
      acc.x = fmaf(p.w, xv.x, acc.x);
      acc.y = fmaf(p.w, xv.y, acc.y);
      acc.z = fmaf(p.w, xv.z, acc.z);
      acc.w = fmaf(p.w, xv.w, acc.w);
    }
    return acc;
  };

  // ---- layer 0: 2048 branches ----
  #pragma unroll
  for (int i = 0; i < 4; ++i) {
    const int j = t + 512*i;
    const float4 e  = dot32(table + OFF_E0 + j, 2048, sx);
    const float4 iv = dot32(table + OFF_I0 + j, 2048, si);
    h0[j][0] = __float2half(e.x / (e.x + 1.f + iv.x));
    h0[j][1] = __float2half(e.y / (e.y + 1.f + iv.y));
    h0[j][2] = __float2half(e.z / (e.z + 1.f + iv.z));
    h0[j][3] = __float2half(e.w / (e.w + 1.f + iv.w));
  }
  __syncthreads();

  // ---- layer 1: 512 branches, aggregate 4 children ----
  {
    const int j = t;
    if (j < 512) {
      const float4 e  = dot32(table + OFF_E1 + j, 512, sx);
      const float4 iv = dot32(table + OFF_I1 + j, 512, si);
      const float4 bw = ((const float4*)bw1)[j];
      const float wsum = bw.x + bw.y + bw.z + bw.w;
      const float ev[4]  = {e.x, e.y, e.z, e.w};
      const float ivv[4] = {iv.x, iv.y, iv.z, iv.w};
      #pragma unroll
      for (int jj = 0; jj < 4; ++jj) {
        const float cur = bw.x*__half2float(h0[4*j+0][jj])
                        + bw.y*__half2float(h0[4*j+1][jj])
                        + bw.z*__half2float(h0[4*j+2][jj])
                        + bw.w*__half2float(h0[4*j+3][jj]);
        const float num = ev[jj] + cur;
        const float den = ev[jj] + 1.f + wsum + ivv[jj];
        h1[j][jj] = __float2half(num / den);
      }
    }
  }
  __syncthreads();

  // ---- soma: 128, aggregate 4 children, rate nonlinearity ----
  if (t < 128) {
    const int s = t;
    const float4 e  = dot32(table + OFF_ES + s, 128, sx);
    const float4 iv = dot32(table + OFF_IS + s, 128, si);
    const float4 bw = ((const float4*)bws)[s];
    const float wsum = bw.x + bw.y + bw.z + bw.w;
    const float vth = 1.f / (1.f + expf(-vthp[s]));
    const float al  = expf(lam[s]);
    const float ev[4]  = {e.x, e.y, e.z, e.w};
    const float ivv[4] = {iv.x, iv.y, iv.z, iv.w};
    #pragma unroll
    for (int jj = 0; jj < 4; ++jj) {
      const float cur = bw.x*__half2float(h1[4*s+0][jj])
                      + bw.y*__half2float(h1[4*s+1][jj])
                      + bw.z*__half2float(h1[4*s+2][jj])
                      + bw.w*__half2float(h1[4*s+3][jj]);
      const float num = ev[jj] + cur;
      const float den = ev[jj] + 1.f + wsum + ivv[jj];
      const float vv = num / den;
      const float vd = vv - vth;
      out[(b0 + jj)*128 + s] = (vd < 0.f) ? 0.f : al * vd * vd;
    }
  }
}

extern "C" void kernel_launch(void* const* d_in, const int* in_sizes, int n_in,
                              void* d_out, int out_size, void* d_ws, size_t ws_size,
                              hipStream_t stream) {
  const float* x    = (const float*)d_in[0];
  const float* inh  = (const float*)d_in[1];
  const float* e0   = (const float*)d_in[2];
  const float* i0   = (const float*)d_in[3];
  const float* e1   = (const float*)d_in[4];
  const float* i1   = (const float*)d_in[5];
  const float* bw1  = (const float*)d_in[6];
  const float* es   = (const float*)d_in[7];
  const float* is_  = (const float*)d_in[8];
  const float* bws  = (const float*)d_in[9];
  const float* vthp = (const float*)d_in[10];
  const float* lam  = (const float*)d_in[11];
  Pair* table = (Pair*)d_ws;
  float* out  = (float*)d_out;

  hipLaunchKernelGGL(topk_kernel, dim3(5376), dim3(256), 0, stream,
                     e0, i0, e1, i1, es, is_, table);
  hipLaunchKernelGGL(fused_kernel, dim3(4096/4), dim3(512), 0, stream,
                     x, inh, bw1, bws, vthp, lam, table, out);
}

// Round 6
// 337.849 us; speedup vs baseline: 1.5931x; 1.5931x over previous
//
#include <hip/hip_runtime.h>
#include <hip/hip_fp16.h>

#define D 4096
#define KSEL 32

struct Pair { unsigned idx; float w; };

// Table layout in d_ws (units: Pair, 8 B). Transposed [k][neuron] per matrix.
constexpr int OFF_E0 = 0;        // 32 x 2048
constexpr int OFF_I0 = 65536;    // 32 x 2048
constexpr int OFF_E1 = 131072;   // 32 x 512
constexpr int OFF_I1 = 147456;   // 32 x 512
constexpr int OFF_ES = 163840;   // 32 x 128
constexpr int OFF_IS = 167936;   // 32 x 128
// total 172032 Pairs = 1,376,256 bytes of workspace

__device__ __forceinline__ unsigned f2key(float f) {
  // order-preserving map: larger float <-> larger unsigned key
  unsigned u = __float_as_uint(f);
  return (u & 0x80000000u) ? ~u : (u | 0x80000000u);
}
__device__ __forceinline__ float key2f(unsigned k) {
  unsigned u = (k & 0x80000000u) ? (k ^ 0x80000000u) : ~k;
  return __uint_as_float(u);
}

// ---------------------------------------------------------------------------
// Kernel 1: exact top-32 SET per row via interval (power-of-2 radix) select.
// Only the selected SET matters (reference builds a mask), so no ordering.
// Ties at the boundary value: smallest indices win (lax.top_k stability).
// One block of 256 threads per row; each thread holds 16 keys in registers.
// ---------------------------------------------------------------------------
__global__ __launch_bounds__(256) void topk_kernel(
    const float* __restrict__ e0, const float* __restrict__ i0,
    const float* __restrict__ e1, const float* __restrict__ i1,
    const float* __restrict__ es, const float* __restrict__ is_,
    Pair* __restrict__ table)
{
  const int rblk = blockIdx.x;
  const float* src; int j; Pair* out; int N;
  if (rblk < 2048)      { src = e0 + (size_t)rblk*D;        j = rblk;      out = table + OFF_E0; N = 2048; }
  else if (rblk < 4096) { src = i0 + (size_t)(rblk-2048)*D; j = rblk-2048; out = table + OFF_I0; N = 2048; }
  else if (rblk < 4608) { src = e1 + (size_t)(rblk-4096)*D; j = rblk-4096; out = table + OFF_E1; N = 512; }
  else if (rblk < 5120) { src = i1 + (size_t)(rblk-4608)*D; j = rblk-4608; out = table + OFF_I1; N = 512; }
  else if (rblk < 5248) { src = es + (size_t)(rblk-5120)*D; j = rblk-5120; out = table + OFF_ES; N = 128; }
  else                  { src = is_ + (size_t)(rblk-5248)*D; j = rblk-5248; out = table + OFF_IS; N = 128; }

  const int t = threadIdx.x;
  const int lane = t & 63;

  // ---- load 16 elements as 4x float4; element id of key[4u+c] = 4t + 1024u + c
  float4 f4[4];
  #pragma unroll
  for (int u = 0; u < 4; ++u) f4[u] = ((const float4*)src)[t + 256*u];
  unsigned key[16];
  #pragma unroll
  for (int u = 0; u < 4; ++u) {
    const float* p = (const float*)&f4[u];
    #pragma unroll
    for (int c = 0; c < 4; ++c) key[4*u + c] = f2key(p[c]);
  }

  __shared__ unsigned hist[256];
  __shared__ unsigned smin[4], smax[4];
  __shared__ unsigned s_lo, s_r;
  __shared__ unsigned long long s_w;
  __shared__ unsigned s_cnt, s_tcnt;
  __shared__ unsigned ties[4096];

  // ---- block min/max of keys (tight interval -> uniform bins, low atomic contention)
  unsigned kmin = key[0], kmax = key[0];
  #pragma unroll
  for (int u = 1; u < 16; ++u) { kmin = min(kmin, key[u]); kmax = max(kmax, key[u]); }
  #pragma unroll
  for (int off = 32; off >= 1; off >>= 1) {
    kmin = min(kmin, (unsigned)__shfl_xor((int)kmin, off));
    kmax = max(kmax, (unsigned)__shfl_xor((int)kmax, off));
  }
  if (lane == 0) { smin[t >> 6] = kmin; smax[t >> 6] = kmax; }
  __syncthreads();
  kmin = min(min(smin[0], smin[1]), min(smin[2], smin[3]));
  kmax = max(max(smax[0], smax[1]), max(smax[2], smax[3]));

  unsigned lo = kmin;
  unsigned long long width = (unsigned long long)kmax - kmin + 1ull;
  unsigned r = KSEL;   // how many to select within current interval

  for (int pass = 0; pass < 6 && width > 1; ++pass) {
    const int sshift = (width <= 256) ? 0 : (56 - __builtin_clzll(width - 1));
    hist[t] = 0;
    __syncthreads();
    #pragma unroll
    for (int u = 0; u < 16; ++u) {
      unsigned long long d = (unsigned long long)key[u] - (unsigned long long)lo;
      if (d < width) atomicAdd(&hist[(unsigned)(d >> sshift)], 1u);
    }
    __syncthreads();
    if (t < 64) {
      const unsigned h0 = hist[4*t+0], h1 = hist[4*t+1], h2 = hist[4*t+2], h3 = hist[4*t+3];
      const unsigned sl = h0 + h1 + h2 + h3;
      unsigned suf = sl;                       // suffix sum over lanes t..63
      #pragma unroll
      for (int off = 1; off < 64; off <<= 1) {
        unsigned o = (unsigned)__shfl_down((int)suf, off);
        if (t + off < 64) suf += o;
      }
      const unsigned long long m = __ballot(suf >= r);   // lanes 0..lstar
      const int lstar = 63 - __builtin_clzll(m);
      if (t == lstar) {
        unsigned c = suf - sl;                 // count strictly above my 4 bins
        int b; unsigned hb;
        c += h3; if (c >= r) { b = 3; hb = h3; }
        else { c += h2; if (c >= r) { b = 2; hb = h2; }
        else { c += h1; if (c >= r) { b = 1; hb = h1; }
        else { c += h0;              { b = 0; hb = h0; } } } }
        const unsigned long long off64 = (unsigned long long)(4*lstar + b) << sshift;
        const unsigned long long rem = width - off64;
        s_lo = lo + (unsigned)off64;
        s_w  = ((1ull << sshift) < rem) ? (1ull << sshift) : rem;
        s_r  = r - (c - hb);
      }
    }
    __syncthreads();
    lo = s_lo; width = s_w; r = s_r;
  }

  // ---- emit: all keys > T, plus r smallest-index ties at T
  const unsigned T = lo;
  if (t == 0) { s_cnt = 0; s_tcnt = 0; }
  __syncthreads();
  #pragma unroll
  for (int u = 0; u < 16; ++u) {
    const unsigned idx = (unsigned)(4*t + 1024*(u >> 2) + (u & 3));
    if (key[u] > T) {
      const unsigned slot = atomicAdd(&s_cnt, 1u);
      out[slot*N + j] = Pair{ idx, expf(key2f(key[u])) };
    } else if (key[u] == T) {
      const unsigned p = atomicAdd(&s_tcnt, 1u);
      if (p < 4096u) ties[p] = idx;
    }
  }
  __syncthreads();
  const unsigned tcnt = min(s_tcnt, 4096u);
  const float tw = expf(key2f(T));
  for (unsigned i = t; i < tcnt; i += 256) {
    const unsigned my = ties[i];
    unsigned rank = 0;
    for (unsigned q = 0; q < tcnt; ++q) rank += (ties[q] < my) ? 1u : 0u;
    if (rank < r) {
      const unsigned slot = atomicAdd(&s_cnt, 1u);
      out[slot*N + j] = Pair{ my, tw };
    }
  }
}

// ---------------------------------------------------------------------------
// Kernel 2: fully fused forward for 4 batch rows per block. (unchanged)
// ---------------------------------------------------------------------------
__global__ __launch_bounds__(512) void fused_kernel(
    const float* __restrict__ x, const float* __restrict__ inh,
    const float* __restrict__ bw1, const float* __restrict__ bws,
    const float* __restrict__ vthp, const float* __restrict__ lam,
    const Pair* __restrict__ table, float* __restrict__ out)
{
  __shared__ float4 sx[D];          // 64 KiB: sx[c] = {x[b0..b3, c]}
  __shared__ float4 si[D];          // 64 KiB
  __shared__ __half h0[2048][4];    // 16 KiB
  __shared__ __half h1[512][4];     //  4 KiB   -> 148 KiB total

  const int t = threadIdx.x;
  const size_t b0 = (size_t)blockIdx.x * 4;

  #pragma unroll
  for (int jj = 0; jj < 4; ++jj) {
    const float* rx = x   + (b0 + jj)*D;
    const float* ri = inh + (b0 + jj)*D;
    #pragma unroll
    for (int i = 0; i < 8; ++i) {
      const int c = t + 512*i;
      ((float*)&sx[c])[jj] = rx[c];
      ((float*)&si[c])[jj] = ri[c];
    }
  }
  __syncthreads();

  auto dot32 = [](const Pair* __restrict__ tb, int stride, const float4* __restrict__ lds) {
    float4 acc = {0.f, 0.f, 0.f, 0.f};
    #pragma unroll 8
    for (int k = 0; k < KSEL; ++k) {
      const Pair p = tb[k*stride];
      const float4 xv = lds[p.idx];
      acc.x = fmaf(p.w, xv.x, acc.x);
      acc.y = fmaf(p.w, xv.y, acc.y);
      acc.z = fmaf(p.w, xv.z, acc.z);
      acc.w = fmaf(p.w, xv.w, acc.w);
    }
    return acc;
  };

  // ---- layer 0: 2048 branches ----
  #pragma unroll
  for (int i = 0; i < 4; ++i) {
    const int j = t + 512*i;
    const float4 e  = dot32(table + OFF_E0 + j, 2048, sx);
    const float4 iv = dot32(table + OFF_I0 + j, 2048, si);
    h0[j][0] = __float2half(e.x / (e.x + 1.f + iv.x));
    h0[j][1] = __float2half(e.y / (e.y + 1.f + iv.y));
    h0[j][2] = __float2half(e.z / (e.z + 1.f + iv.z));
    h0[j][3] = __float2half(e.w / (e.w + 1.f + iv.w));
  }
  __syncthreads();

  // ---- layer 1: 512 branches, aggregate 4 children ----
  if (t < 512) {
    const int j = t;
    const float4 e  = dot32(table + OFF_E1 + j, 512, sx);
    const float4 iv = dot32(table + OFF_I1 + j, 512, si);
    const float4 bw = ((const float4*)bw1)[j];
    const float wsum = bw.x + bw.y + bw.z + bw.w;
    const float ev[4]  = {e.x, e.y, e.z, e.w};
    const float ivv[4] = {iv.x, iv.y, iv.z, iv.w};
    #pragma unroll
    for (int jj = 0; jj < 4; ++jj) {
      const float cur = bw.x*__half2float(h0[4*j+0][jj])
                      + bw.y*__half2float(h0[4*j+1][jj])
                      + bw.z*__half2float(h0[4*j+2][jj])
                      + bw.w*__half2float(h0[4*j+3][jj]);
      const float num = ev[jj] + cur;
      const float den = ev[jj] + 1.f + wsum + ivv[jj];
      h1[j][jj] = __float2half(num / den);
    }
  }
  __syncthreads();

  // ---- soma: 128, aggregate 4 children, rate nonlinearity ----
  if (t < 128) {
    const int s = t;
    const float4 e  = dot32(table + OFF_ES + s, 128, sx);
    const float4 iv = dot32(table + OFF_IS + s, 128, si);
    const float4 bw = ((const float4*)bws)[s];
    const float wsum = bw.x + bw.y + bw.z + bw.w;
    const float vth = 1.f / (1.f + expf(-vthp[s]));
    const float al  = expf(lam[s]);
    const float ev[4]  = {e.x, e.y, e.z, e.w};
    const float ivv[4] = {iv.x, iv.y, iv.z, iv.w};
    #pragma unroll
    for (int jj = 0; jj < 4; ++jj) {
      const float cur = bw.x*__half2float(h1[4*s+0][jj])
                      + bw.y*__half2float(h1[4*s+1][jj])
                      + bw.z*__half2float(h1[4*s+2][jj])
                      + bw.w*__half2float(h1[4*s+3][jj]);
      const float num = ev[jj] + cur;
      const float den = ev[jj] + 1.f + wsum + ivv[jj];
      const float vv = num / den;
      const float vd = vv - vth;
      out[(b0 + jj)*128 + s] = (vd < 0.f) ? 0.f : al * vd * vd;
    }
  }
}

extern "C" void kernel_launch(void* const* d_in, const int* in_sizes, int n_in,
                              void* d_out, int out_size, void* d_ws, size_t ws_size,
                              hipStream_t stream) {
  const float* x    = (const float*)d_in[0];
  const float* inh  = (const float*)d_in[1];
  const float* e0   = (const float*)d_in[2];
  const float* i0   = (const float*)d_in[3];
  const float* e1   = (const float*)d_in[4];
  const float* i1   = (const float*)d_in[5];
  const float* bw1  = (const float*)d_in[6];
  const float* es   = (const float*)d_in[7];
  const float* is_  = (const float*)d_in[8];
  const float* bws  = (const float*)d_in[9];
  const float* vthp = (const float*)d_in[10];
  const float* lam  = (const float*)d_in[11];
  Pair* table = (Pair*)d_ws;
  float* out  = (float*)d_out;

  hipLaunchKernelGGL(topk_kernel, dim3(5376), dim3(256), 0, stream,
                     e0, i0, e1, i1, es, is_, table);
  hipLaunchKernelGGL(fused_kernel, dim3(4096/4), dim3(512), 0, stream,
                     x, inh, bw1, bws, vthp, lam, table, out);
}